// Round 8
// baseline (160.736 us; speedup 1.0000x reference)
//
#include <hip/hip_runtime.h>

// VQ: x (16,64,64,64) f32, codebook e (64,1024) f32. N=65536, D=64, K=1024.
//
// R8 = certified split-bf16 MFMA (R6/R7, absmax 0) with:
//  - A=||x||^2 dropped from scored loop (constant per position: cancels in
//    gaps; certification margin covers the <=2e-5 rounding asymmetry).
//    Kills the 16 MB norms pass. Fallback still uses np-exact A.
//  - 2 tiles/round double-buffer: 24 MFMA/wave between barriers (was 6).
//  - block = 128 pos (wave = 2 M-tiles), grid 512 = 2 blocks/CU (matches
//    observed residency cap instead of assuming 4).
// Numerics: same frag layouts / MFMA order / MARGIN certify / np-bit-exact
// block-local fallback with first-index ties.

#define D 64
#define K 1024
#define NPOS 65536
#define HW 4096
#define XSTRIDE 262144  // D*HW
#define MARGIN 1.0e-3f

typedef float vfloat4 __attribute__((ext_vector_type(4)));
typedef short short8  __attribute__((ext_vector_type(8)));

static __device__ __forceinline__ unsigned short bf16_rne(float f) {
    unsigned u = __float_as_uint(f);
    u += 0x7FFFu + ((u >> 16) & 1u);
    return (unsigned short)(u >> 16);
}
static __device__ __forceinline__ float bf16_to_f32(unsigned short h) {
    return __uint_as_float(((unsigned)h) << 16);
}

// ---- prep: blocks 0..63 frags+eT, 64..67 c2 (no norms pass anymore) ------
__global__ __launch_bounds__(256)
void vq_prep(const float* __restrict__ e,
             unsigned short* __restrict__ ebf, float* __restrict__ eT,
             float* __restrict__ c2) {
    const int blk = blockIdx.x;
    const int t = threadIdx.x;
    if (blk < 64) {
        const int tile = blk;
        const int n = t & 15, dg = t >> 4;
#pragma unroll
        for (int i = 0; i < 4; ++i) {
            const int d = dg * 4 + i;
            const int k = tile * 16 + n;
            const float v = e[d * K + k];
            eT[k * 64 + d] = v;                       // fp32 row copy
            const unsigned short hh = bf16_rne(v);
            const float rem = v - bf16_to_f32(hh);    // exact
            const unsigned short hl = bf16_rne(rem);
            const int s = d >> 5, q = (d >> 3) & 3, j = d & 7;
            const int lanei = q * 16 + n;
            ebf[(((tile * 2 + s) * 2 + 0) * 64 + lanei) * 8 + j] = hh;
            ebf[(((tile * 2 + s) * 2 + 1) * 64 + lanei) * 8 + j] = hl;
        }
    } else {
        const int k = (blk - 64) * 256 + t;
        float s = 0.f;
#pragma unroll
        for (int d = 0; d < D; ++d) {                 // np axis-0: sequential
            const float v = e[d * K + k];
            s = s + __fmul_rn(v, v);
        }
        c2[k] = s;
    }
}

// ---- main: 512 blocks x 256; block = 128 pos; wave = 2 M-tiles -----------
__global__ __launch_bounds__(256, 2)
void vq_main(const float* __restrict__ x, const float* __restrict__ e,
             const unsigned short* __restrict__ ebf,
             const float* __restrict__ eT,
             const float* __restrict__ c2g, float* __restrict__ out) {
    __shared__ short8 fb[2][2][2][2][64]; // [buf][tp][ktile][split][lane] 16KB
    __shared__ float  c2_lds[K];          // 4 KB
    __shared__ float  q_lds[64][65];      // 16.6 KB, pad-65: conflict-free
    __shared__ int    bk_lds[128];
    __shared__ int    amb_cnt;
    __shared__ int    amb_list[128];
    __shared__ float  xa[64];
    __shared__ float  aShared;
    __shared__ float  rs[256];
    __shared__ int    rk[256];

    const int t    = threadIdx.x;
    const int lane = t & 63;
    const int w    = t >> 6;
    const int n    = lane & 15;          // code-within-tile / A-row index
    const int q    = lane >> 4;          // k-quad / C row group
    const int p0   = blockIdx.x * 128;
    const int b    = p0 >> 12;
    const int sp0  = p0 & (HW - 1);

    if (t == 0) amb_cnt = 0;
    ((vfloat4*)c2_lds)[t] = ((const vfloat4*)c2g)[t];

    // ---- A-frags (registers): split-bf16, 2 M-tiles; NO norm term
    short8 ah[2][2], al[2][2];
#pragma unroll
    for (int mt = 0; mt < 2; ++mt) {
        const int spc = sp0 + w * 32 + mt * 16 + n;
#pragma unroll
        for (int s = 0; s < 2; ++s) {
            short8 fh, fl_;
#pragma unroll
            for (int j = 0; j < 8; ++j) {
                const int d = s * 32 + q * 8 + j;     // A[m=n][k=q*8+j]
                const float v = x[(size_t)b * XSTRIDE + (size_t)d * HW + spc];
                const unsigned short h = bf16_rne(v);
                fh[j] = (short)h;
                fl_[j] = (short)bf16_rne(v - bf16_to_f32(h));
            }
            ah[mt][s] = fh; al[mt][s] = fl_;
        }
    }

    // ---- stage round 0 (tiles 0,1): 2x 16B per thread
#pragma unroll
    for (int tp = 0; tp < 2; ++tp) {
        const char* src = (const char*)ebf + (size_t)tp * 4096 + t * 16;
        char* dst = (char*)(&fb[0][tp][0][0][0]) + t * 16;
        __builtin_amdgcn_global_load_lds(
            (const __attribute__((address_space(1))) unsigned int*)src,
            (__attribute__((address_space(3))) unsigned int*)dst, 16, 0, 0);
    }
    __syncthreads();

    float s1v[2][4], s2v[2][4]; int t1v[2][4];
#pragma unroll
    for (int mt = 0; mt < 2; ++mt)
#pragma unroll
        for (int r = 0; r < 4; ++r) { s1v[mt][r] = 3.4e38f; s2v[mt][r] = 3.4e38f; t1v[mt][r] = 0; }

    for (int rdx = 0; rdx < 32; ++rdx) {
        const int buf = rdx & 1;
        if (rdx < 31) {                  // prefetch next 2 tiles, other buffer
#pragma unroll
            for (int tp = 0; tp < 2; ++tp) {
                const char* src = (const char*)ebf
                    + (size_t)(2 * rdx + 2 + tp) * 4096 + t * 16;
                char* dst = (char*)(&fb[buf ^ 1][tp][0][0][0]) + t * 16;
                __builtin_amdgcn_global_load_lds(
                    (const __attribute__((address_space(1))) unsigned int*)src,
                    (__attribute__((address_space(3))) unsigned int*)dst, 16, 0, 0);
            }
        }
#pragma unroll
        for (int tp = 0; tp < 2; ++tp) {               // 24 MFMA per round
            const int tile = 2 * rdx + tp;
            const short8 bh0 = fb[buf][tp][0][0][lane];
            const short8 bl0 = fb[buf][tp][0][1][lane];
            const short8 bh1 = fb[buf][tp][1][0][lane];
            const short8 bl1 = fb[buf][tp][1][1][lane];
            const float c2v = c2_lds[tile * 16 + n];   // broadcast: no conf
#pragma unroll
            for (int mt = 0; mt < 2; ++mt) {
                vfloat4 acc = {0.f, 0.f, 0.f, 0.f};    // same order as R6/R7
                acc = __builtin_amdgcn_mfma_f32_16x16x32_bf16(ah[mt][0], bh0, acc, 0, 0, 0);
                acc = __builtin_amdgcn_mfma_f32_16x16x32_bf16(ah[mt][1], bh1, acc, 0, 0, 0);
                acc = __builtin_amdgcn_mfma_f32_16x16x32_bf16(al[mt][0], bh0, acc, 0, 0, 0);
                acc = __builtin_amdgcn_mfma_f32_16x16x32_bf16(al[mt][1], bh1, acc, 0, 0, 0);
                acc = __builtin_amdgcn_mfma_f32_16x16x32_bf16(ah[mt][0], bl0, acc, 0, 0, 0);
                acc = __builtin_amdgcn_mfma_f32_16x16x32_bf16(ah[mt][1], bl1, acc, 0, 0, 0);
#pragma unroll
                for (int r = 0; r < 4; ++r) {          // top-2, s1<=s2
                    const float sc = __builtin_fmaf(-2.f, acc[r], c2v);
                    const bool lt1 = sc < s1v[mt][r];
                    s2v[mt][r] = fminf(fmaxf(sc, s1v[mt][r]), s2v[mt][r]);
                    s1v[mt][r] = fminf(s1v[mt][r], sc);
                    t1v[mt][r] = lt1 ? tile : t1v[mt][r];
                }
            }
        }
        __syncthreads();                 // next buf staged; buf reads done
    }

    // ---- merge top-2 across 16 code-columns (butterfly over n)
#pragma unroll
    for (int mt = 0; mt < 2; ++mt)
#pragma unroll
        for (int r = 0; r < 4; ++r) {
            float a1 = s1v[mt][r], a2 = s2v[mt][r];
            int ak = t1v[mt][r] * 16 + n;
#pragma unroll
            for (int m = 1; m < 16; m <<= 1) {
                const float o1 = __shfl_xor(a1, m, 64);
                const float o2 = __shfl_xor(a2, m, 64);
                const int   ok = __shfl_xor(ak, m, 64);
                const bool take = (o1 < a1) || (o1 == a1 && ok < ak);
                const float loser = take ? a1 : o1;
                a1 = take ? o1 : a1;
                ak = take ? ok : ak;
                a2 = fminf(fminf(a2, o2), loser);
            }
            if (n == 0) {
                const int pl = w * 32 + mt * 16 + q * 4 + r;
                bk_lds[pl] = ak;
                if (a2 - a1 <= MARGIN) {               // uncertified
                    const int idx = atomicAdd(&amb_cnt, 1);
                    amb_list[idx] = pl;
                }
            }
        }
    __syncthreads();

    // ---- epilogue: 2 half-rounds of 64 positions through q_lds
#pragma unroll
    for (int half = 0; half < 2; ++half) {
        {
            const int row = t >> 2, seg = t & 3;
            const float* er = eT + (size_t)bk_lds[half * 64 + row] * 64 + seg * 16;
#pragma unroll
            for (int i = 0; i < 4; ++i)
                *(vfloat4*)(&q_lds[row][seg * 16 + i * 4]) = *(const vfloat4*)(er + i * 4);
        }
        __syncthreads();
        {
            const int pl = t & 63, grp = t >> 6;
            const int sp = sp0 + half * 64 + pl;
            const float* xb = x + (size_t)b * XSTRIDE + sp;
            float* ob = out + (size_t)b * XSTRIDE + sp;
#pragma unroll
            for (int i = 0; i < 16; ++i) {
                const int c = grp * 16 + i;
                const float xq = xb[(size_t)c * HW];   // coalesced
                const float qv = q_lds[pl][c];         // 2-way: free
                ob[(size_t)c * HW] = xq + (qv - xq);   // np STE
            }
        }
        __syncthreads();
    }

    // ---- block-local np-bit-exact fallback (rare)
    const int na = amb_cnt;
    for (int ai = 0; ai < na; ++ai) {
        const int pl = amb_list[ai];
        const int sp = sp0 + pl;
        if (t < 64) xa[t] = x[(size_t)b * XSTRIDE + (size_t)t * HW + sp];
        __syncthreads();
        if (t == 0) {                    // np A: pairwise-8, rounded squares
            float r8[8];
#pragma unroll
            for (int i = 0; i < 8; ++i) r8[i] = __fmul_rn(xa[i], xa[i]);
#pragma unroll
            for (int j = 1; j < 8; ++j)
#pragma unroll
                for (int i = 0; i < 8; ++i)
                    r8[i] = r8[i] + __fmul_rn(xa[8 * j + i], xa[8 * j + i]);
            aShared = ((r8[0]+r8[1])+(r8[2]+r8[3])) + ((r8[4]+r8[5])+(r8[6]+r8[7]));
        }
        __syncthreads();
        const float Ap = aShared;
        float bs = 3.4e38f; int bkk = 0x7fffffff;
#pragma unroll
        for (int j = 0; j < 4; ++j) {
            const int k = t + 256 * j;                 // ascending k
            float acc = 0.f;
            for (int d = 0; d < D; ++d)                // sequential-d chain
                acc = __builtin_fmaf(xa[d], e[d * K + k], acc);
            const float sc = __builtin_fmaf(-2.f, acc, Ap) + c2_lds[k];
            if (sc < bs || (sc == bs && k < bkk)) { bs = sc; bkk = k; }
        }
        rs[t] = bs; rk[t] = bkk;
        __syncthreads();
        for (int off = 128; off > 0; off >>= 1) {
            if (t < off) {
                const float so = rs[t + off]; const int ko = rk[t + off];
                if (so < rs[t] || (so == rs[t] && ko < rk[t])) { rs[t] = so; rk[t] = ko; }
            }
            __syncthreads();
        }
        const int kb = rk[0];
        if (t < 64) {
            const float xq = xa[t];
            const float qv = eT[(size_t)kb * 64 + t];
            out[(size_t)b * XSTRIDE + (size_t)t * HW + sp] = xq + (qv - xq);
        }
        __syncthreads();
    }
}

extern "C" void kernel_launch(void* const* d_in, const int* in_sizes, int n_in,
                              void* d_out, int out_size, void* d_ws, size_t ws_size,
                              hipStream_t stream) {
    const float* x = (const float*)d_in[0];
    const float* e = (const float*)d_in[1];
    float* out = (float*)d_out;

    char* ws = (char*)d_ws;                          // 516 KB used
    unsigned short* ebf = (unsigned short*)ws;       // 256 KB B-fragments
    float* eT = (float*)(ws + 262144);               // 256 KB fp32 rows
    float* c2 = (float*)(ws + 524288);               // 4 KB

    vq_prep<<<68, 256, 0, stream>>>(e, ebf, eT, c2);
    vq_main<<<NPOS / 128, 256, 0, stream>>>(x, e, ebf, eT, c2, out);
}